// Round 9
// baseline (279.864 us; speedup 1.0000x reference)
//
#include <hip/hip_runtime.h>

#define VV 3
#define NN 6000
#define DD 512
#define HH 256
#define DYY 512
#define NPAD 6016   // 47*128
#define QK_BK 32
#define QK_BUF (192 * QK_BK)   // u16 per ring slot: A 64 rows + B 128 rows (12288 B)

typedef unsigned short u16;
typedef unsigned char u8;
typedef __bf16 bf16x8 __attribute__((ext_vector_type(8)));
typedef u16 u16x8 __attribute__((ext_vector_type(8)));
typedef float f32x4 __attribute__((ext_vector_type(4)));
typedef float f32x2 __attribute__((ext_vector_type(2)));
typedef u16 u16x4 __attribute__((ext_vector_type(4)));
typedef unsigned int u32x4 __attribute__((ext_vector_type(4)));

__device__ __forceinline__ u16 f2bf(float f) {
  unsigned int b = __builtin_bit_cast(unsigned int, f);
  b += 0x7FFFu + ((b >> 16) & 1u);
  return (u16)(b >> 16);
}
__device__ __forceinline__ float bf2f(u16 u) {
  unsigned int b = ((unsigned int)u) << 16;
  return __builtin_bit_cast(float, b);
}
// hardware OCP e4m3fn convert (RNE, saturating) — 1 inst vs ~20 for manual
__device__ __forceinline__ u8 f2fp8_hw(float f) {
  unsigned int r;
  asm("v_cvt_pk_fp8_f32 %0, %1, %2" : "=v"(r) : "v"(f), "v"(f));
  return (u8)(r & 0xffu);
}
__device__ __forceinline__ float fp82f_hw(u8 b) {
  f32x2 lo = __builtin_amdgcn_cvt_pk_f32_fp8((int)b, false);
  return lo[0];
}
__device__ __forceinline__ float leaky(float v) { return v >= 0.0f ? v : 0.1f * v; }

// ---- swizzled DEPTH=32 stage: 16B chunk c of row r lands at LDS slot c^((r>>1)&3)
// (conflict-free ds_read_b128: 8 consecutive lanes cover all 8 bank groups)
template<int ROWS>
__device__ __forceinline__ void stage_sw(const u16* __restrict__ g, int ld, u16* s, int wave, int lane) {
  constexpr int PER = ROWS / 4;    // 4 lanes/row
  int rin = lane >> 2, c = lane & 3;
#pragma unroll
  for (int ch = 0; ch < PER / 16; ++ch) {
    int rloc = wave * PER + ch * 16 + rin;
    const u16* gp = g + (size_t)rloc * ld + ((c ^ ((rloc >> 1) & 3)) << 3);
    u16* sp = s + (wave * PER + ch * 16) * 32;   // linear dest; lane at +16B*lane
    __builtin_amdgcn_global_load_lds(
        (const __attribute__((address_space(1))) void*)gp,
        (__attribute__((address_space(3))) void*)sp, 16, 0, 0);
  }
}

// ---- fp8 stage: ROWS x 64-byte rows with 16-B-chunk XOR swizzle (bank-conflict-free reads)
__device__ __forceinline__ int swz4(int r) { return (r & 3) ^ ((r >> 2) & 3); }
template<int ROWS>
__device__ __forceinline__ void stage8(const u8* __restrict__ g, int ld, u8* s, int wave, int lane) {
  constexpr int PER = ROWS / 4;    // rows per wave (4 lanes/row, 16 rows per 64-lane chunk)
  int rin = lane >> 2, c = lane & 3;
#pragma unroll
  for (int ch = 0; ch < PER / 16; ++ch) {
    int rloc = wave * PER + ch * 16 + rin;
    const u8* gp = g + (size_t)rloc * ld + ((c ^ swz4(rloc)) << 4);
    u8* sp = s + (wave * PER + ch * 16) * 64;   // wave-uniform; lane lands at +16B*lane
    __builtin_amdgcn_global_load_lds(
        (const __attribute__((address_space(1))) void*)gp,
        (__attribute__((address_space(3))) void*)sp, 16, 0, 0);
  }
}

// swizzled-read MFMA step, DEPTH=32 (matches stage_sw layout): 64x128 block tile
__device__ __forceinline__ void mfma_step_sw(const u16* As, const u16* Bs, f32x4 (*acc)[4], int lane, int wave) {
  const int wr = (wave >> 1) * 32;
  const int wc = (wave & 1) * 64;
  const int l15 = lane & 15, lq = lane >> 4;
  bf16x8 a[2], b[4];
#pragma unroll
  for (int i = 0; i < 2; ++i) {
    int r = wr + i * 16 + l15;
    a[i] = *(const bf16x8*)(As + r * 32 + ((lq ^ ((r >> 1) & 3)) << 3));
  }
#pragma unroll
  for (int j = 0; j < 4; ++j) {
    int r = wc + j * 16 + l15;
    b[j] = *(const bf16x8*)(Bs + r * 32 + ((lq ^ ((r >> 1) & 3)) << 3));
  }
#pragma unroll
  for (int i = 0; i < 2; ++i)
#pragma unroll
    for (int j = 0; j < 4; ++j)
      acc[i][j] = __builtin_amdgcn_mfma_f32_16x16x32_bf16(a[i], b[j], acc[i][j], 0, 0, 0);
}

// fp8 MFMA step: 128x128 tile, 64 K-elems (64 B) per slice, swizzled LDS
__device__ __forceinline__ void mfma_step8(const u8* As, const u8* Bs, f32x4 (*acc)[4], int lane, int wave) {
  const int wr = (wave >> 1) * 64;
  const int wc = (wave & 1) * 64;
  const int l15 = lane & 15, lq = lane >> 4;
#pragma unroll
  for (int kk = 0; kk < 64; kk += 32) {
    long a[4], b[4];
    int gch = (kk >> 4) + (lq >> 1), half = (lq & 1) << 3;
#pragma unroll
    for (int i = 0; i < 4; ++i) {
      int r = wr + i * 16 + l15;
      a[i] = *(const long*)(As + r * 64 + ((gch ^ swz4(r)) << 4) + half);
    }
#pragma unroll
    for (int j = 0; j < 4; ++j) {
      int r = wc + j * 16 + l15;
      b[j] = *(const long*)(Bs + r * 64 + ((gch ^ swz4(r)) << 4) + half);
    }
#pragma unroll
    for (int i = 0; i < 4; ++i)
#pragma unroll
      for (int j = 0; j < 4; ++j)
        acc[i][j] = __builtin_amdgcn_mfma_f32_16x16x32_fp8_fp8(a[i], b[j], acc[i][j], 0, 0, 0);
  }
}

// ring-3 single-barrier counted-vmcnt bf16 K-loop (k_qk-proven structure).
// Per stage: 3 global_load_lds/wave (A 64 rows: 1, B 128 rows: 2) -> vmcnt(3)
// means "stage(it) done, stage(it+1) in flight". 36864 B LDS -> 4 blocks/CU.
__device__ __forceinline__ void gemm_loop_r3(const u16* __restrict__ A, int lda,
                                             const u16* __restrict__ B, int ldb, int K,
                                             u16* sh, f32x4 (*acc)[4], int lane, int wave) {
  const int niter = K / 32;
  auto st = [&](int it, u16* buf) {
    stage_sw<64>(A + it * 32, lda, buf, wave, lane);
    stage_sw<128>(B + it * 32, ldb, buf + 64 * 32, wave, lane);
  };
  st(0, sh);
  st(1, sh + QK_BUF);
  for (int it = 0; it < niter; ++it) {
    if (it == niter - 1) asm volatile("s_waitcnt vmcnt(0)" ::: "memory");
    else                 asm volatile("s_waitcnt vmcnt(3)" ::: "memory");
    __builtin_amdgcn_sched_barrier(0);
    __builtin_amdgcn_s_barrier();
    __builtin_amdgcn_sched_barrier(0);
    if (it + 2 < niter) st(it + 2, sh + ((it + 2) % 3) * QK_BUF);
    const u16* cur = sh + (it % 3) * QK_BUF;
    __builtin_amdgcn_s_setprio(1);
    mfma_step_sw(cur, cur + 64 * 32, acc, lane, wave);
    __builtin_amdgcn_s_setprio(0);
  }
  __syncthreads();
}

// ---------------- merged prep kernel ----------------

__device__ __forceinline__ void conv4(const float* __restrict__ in, u16* __restrict__ out, int i) {
  float4 f = ((const float4*)in)[i];
  u16x4 o = { f2bf(f.x), f2bf(f.y), f2bf(f.z), f2bf(f.w) };
  *(u16x4*)(out + i * 4) = o;
}

#define N_WIN  (VV * HH * DD / 4)
#define N_WOUT (VV * DD * HH / 4)
#define N_WY   (HH * DYY / 4)
#define N_Y    (NN * DYY / 4)
#define N_X    (VV * NN * DD / 4)
#define N_MT   (VV * NPAD / 4)
#define N_PREP (N_WIN + N_WOUT + N_WY + N_Y + N_X + N_MT)

__global__ __launch_bounds__(256) void k_prep(const float* __restrict__ x, const float* __restrict__ y,
                                              const float* __restrict__ mask,
                                              const float* __restrict__ W_in, const float* __restrict__ W_out,
                                              const float* __restrict__ Wy,
                                              u16* __restrict__ xb, u16* __restrict__ yb,
                                              u16* __restrict__ winb, u16* __restrict__ woutb,
                                              u16* __restrict__ wyb, float* __restrict__ mT) {
  int i = blockIdx.x * 256 + threadIdx.x;
  if (i < N_X) {   // biggest segment first
    int idx = i * 4;
    int v = idx / (NN * DD);
    int rem = idx - v * (NN * DD);
    int n = rem / DD;
    int d = rem - n * DD;
    float4 f = *(const float4*)(x + idx);
    u16x4 o = { f2bf(f.x), f2bf(f.y), f2bf(f.z), f2bf(f.w) };
    *(u16x4*)(xb + (size_t)(v * NPAD + n) * DD + d) = o;
    return;
  }
  i -= N_X;
  if (i < N_Y)  { conv4(y, yb, i); return; }
  i -= N_Y;
  if (i < N_WIN) { conv4(W_in, winb, i); return; }
  i -= N_WIN;
  if (i < N_WOUT){ conv4(W_out, woutb, i); return; }
  i -= N_WOUT;
  if (i < N_WY) { conv4(Wy, wyb, i); return; }
  i -= N_WY;
  if (i < N_MT) {
#pragma unroll
    for (int t = 0; t < 4; ++t) {
      int idx = i * 4 + t;
      int v = idx / NPAD, n = idx - v * NPAD;
      mT[idx] = (n < NN) ? mask[n * VV + v] : 0.0f;
    }
  }
}

// ---------------- fused q-norm + hmT kernel ----------------
// One h pass per 64-row tile: row L2-norm -> qb (bf16), masked fp8 -> LDS tile
// -> transposed hmT write.
__global__ __launch_bounds__(256) void k_qh(const float* __restrict__ h, const float* __restrict__ mT,
                                            u16* __restrict__ qb, u8* __restrict__ hmT) {
  __shared__ u8 t8[64][260];   // 260 = 4*65 (odd word stride -> conflict-free col reads)
  int m0 = blockIdx.x * 64, v = blockIdx.y;
  int lane = threadIdx.x & 63, wave = threadIdx.x >> 6;
#pragma unroll
  for (int rr = 0; rr < 16; ++rr) {
    int row = wave * 16 + rr;
    int m = m0 + row;
    float4 f = *(const float4*)(h + (size_t)(v * NPAD + m) * HH + lane * 4);
    float ss = f.x * f.x + f.y * f.y + f.z * f.z + f.w * f.w;
#pragma unroll
    for (int o = 32; o > 0; o >>= 1) ss += __shfl_xor(ss, o, 64);
    float inv = 1.0f / fmaxf(sqrtf(ss), 1e-12f);
    u16x4 qo = { f2bf(f.x * inv), f2bf(f.y * inv), f2bf(f.z * inv), f2bf(f.w * inv) };
    *(u16x4*)(qb + (size_t)(v * NPAD + m) * HH + lane * 4) = qo;
    float mrow = mT[v * NPAD + m];
    bool ok = (m < NN) && (mrow != 0.0f);   // m>=NN rows are garbage: force 0 (NaN*0 hazard)
    unsigned q0 = f2fp8_hw(ok ? mrow * f.x : 0.0f);
    unsigned q1 = f2fp8_hw(ok ? mrow * f.y : 0.0f);
    unsigned q2 = f2fp8_hw(ok ? mrow * f.z : 0.0f);
    unsigned q3 = f2fp8_hw(ok ? mrow * f.w : 0.0f);
    *(unsigned*)&t8[row][lane * 4] = q0 | (q1 << 8) | (q2 << 16) | (q3 << 24);
  }
  __syncthreads();
  // transposed write: hmT[v][j][m0..m0+63], u32-packed (16 threads x 4B per j-row)
  int m4 = threadIdx.x & 15, jb = threadIdx.x >> 4;
#pragma unroll
  for (int p = 0; p < 16; ++p) {
    int j = jb + p * 16;
    unsigned b0 = t8[m4 * 4 + 0][j], b1 = t8[m4 * 4 + 1][j];
    unsigned b2 = t8[m4 * 4 + 2][j], b3 = t8[m4 * 4 + 3][j];
    *(unsigned*)(hmT + (size_t)(v * HH + j) * NPAD + m0 + m4 * 4) =
        b0 | (b1 << 8) | (b2 << 16) | (b3 << 24);
  }
}

// ---------------- GEMM kernels ----------------

// h = leaky(x @ W_in^T + b_in)  [ring-3 counted-vmcnt loop]
__global__ __launch_bounds__(256, 4) void k_gemm1(const u16* __restrict__ xb, const u16* __restrict__ winb,
                                                  const float* __restrict__ b_in, float* __restrict__ h) {
  __shared__ u16 sh[3 * QK_BUF];
  int lane = threadIdx.x & 63, wave = threadIdx.x >> 6;
  int col0 = blockIdx.x * 128, row0 = blockIdx.y * 64, v = blockIdx.z;
  f32x4 acc[2][4];
  f32x4 z = {0.f, 0.f, 0.f, 0.f};
  for (int i = 0; i < 2; ++i) for (int j = 0; j < 4; ++j) acc[i][j] = z;
  gemm_loop_r3(xb + (size_t)(v * NPAD + row0) * DD, DD,
               winb + (size_t)(v * HH + col0) * DD, DD, DD, sh, acc, lane, wave);
  int wr = (wave >> 1) * 32, wc = (wave & 1) * 64, l15 = lane & 15, lq = lane >> 4;
#pragma unroll
  for (int i = 0; i < 2; ++i)
#pragma unroll
    for (int r = 0; r < 4; ++r) {
      int grow = row0 + wr + i * 16 + lq * 4 + r;
      if (grow < NN) {
#pragma unroll
        for (int j = 0; j < 4; ++j) {
          int gcol = col0 + wc + j * 16 + l15;
          h[(size_t)(v * NPAD + grow) * HH + gcol] = leaky(acc[i][j][r] + b_in[v * HH + gcol]);
        }
      }
    }
}

// A = max_v mask*exp(q_v q_v^T / beta), diag zeroed -> fp8 e4m3; row sums S via
// atomics (upper cell counted in rs for its row, strict-upper mirrored into cs
// for its column — tiling covers each upper-triangle cell exactly once).
// 64x128 tile RT=2, 3-deep ring, single barrier per iter, counted vmcnt(3),
// 36 KB LDS -> 4 blocks/CU. Bijective XCD swizzle (2256 = 8*282).
__global__ __launch_bounds__(256, 4) void k_qk(const u16* __restrict__ qb, const float* __restrict__ mT,
                                               u8* __restrict__ Abf, float* __restrict__ S) {
  __shared__ u16 sh[3 * QK_BUF];   // 36864 B; reused for Dir/Tr in epilogue
  int lane = threadIdx.x & 63, wave = threadIdx.x >> 6;
  int bid = (blockIdx.x & 7) * 282 + (blockIdx.x >> 3);   // XCD swizzle (2256=8*282)
  int x = (int)((sqrtf((float)(4 * bid + 1)) - 1.0f) * 0.5f);
  while ((x + 1) * (x + 2) <= bid) ++x;
  while (x * (x + 1) > bid) --x;
  int y = bid - x * (x + 1);
  int col0 = x * 128, row0 = y * 64;

  const int wr = (wave >> 1) * 32, wc = (wave & 1) * 64;
  const int l15 = lane & 15, lq = lane >> 4;

  // mask bitmasks: rbm bit v*8+i*4+r = (mT[v][grow]!=0); cbm bit v*4+j
  unsigned rbm = 0, cbm = 0;
#pragma unroll
  for (int v = 0; v < VV; ++v) {
#pragma unroll
    for (int t = 0; t < 8; ++t) {
      int grow = row0 + wr + (t >> 2) * 16 + lq * 4 + (t & 3);
      if (mT[v * NPAD + grow] != 0.0f) rbm |= 1u << (v * 8 + t);
    }
#pragma unroll
    for (int j = 0; j < 4; ++j)
      if (mT[v * NPAD + col0 + wc + j * 16 + l15] != 0.0f) cbm |= 1u << (v * 4 + j);
  }
  // pin mask-load consumption here so no compiler vmcnt waits land in the loop
  asm volatile("" : "+v"(rbm), "+v"(cbm));

  f32x4 z = {0.f, 0.f, 0.f, 0.f};
  float ninf = -__builtin_inff();
  f32x4 nv = {ninf, ninf, ninf, ninf};
  f32x4 acc[2][4];
  f32x4 emax[2][4];
  for (int i = 0; i < 2; ++i)
    for (int j = 0; j < 4; ++j) { acc[i][j] = z; emax[i][j] = nv; }

  auto stage_it = [&](int it, u16* buf) {
    int v = it >> 3, k0 = (it & 7) * QK_BK;
    const u16* base = qb + (size_t)v * NPAD * HH + k0;
    stage_sw<64>(base + (size_t)row0 * HH, HH, buf, wave, lane);
    stage_sw<128>(base + (size_t)col0 * HH, HH, buf + 64 * QK_BK, wave, lane);
  };

  const int NIT = VV * (HH / QK_BK);   // 24
  stage_it(0, sh);
  stage_it(1, sh + QK_BUF);
#pragma unroll
  for (int it = 0; it < NIT; ++it) {
    if (it == NIT - 1) asm volatile("s_waitcnt vmcnt(0)" ::: "memory");
    else               asm volatile("s_waitcnt vmcnt(3)" ::: "memory");
    __builtin_amdgcn_sched_barrier(0);
    __builtin_amdgcn_s_barrier();
    __builtin_amdgcn_sched_barrier(0);
    if (it + 2 < NIT) stage_it(it + 2, sh + ((it + 2) % 3) * QK_BUF);
    const u16* cur = sh + (it % 3) * QK_BUF;
    __builtin_amdgcn_s_setprio(1);
    mfma_step_sw(cur, cur + 64 * QK_BK, acc, lane, wave);
    __builtin_amdgcn_s_setprio(0);
    if ((it & 7) == 7) {               // v complete: fold masked scores into emax
      int v = it >> 3;
#pragma unroll
      for (int i = 0; i < 2; ++i)
#pragma unroll
        for (int r = 0; r < 4; ++r) {
          bool rb = (rbm >> (v * 8 + i * 4 + r)) & 1;
#pragma unroll
          for (int j = 0; j < 4; ++j) {
            bool on = rb && ((cbm >> (v * 4 + j)) & 1);
            if (on) emax[i][j][r] = fmaxf(emax[i][j][r], acc[i][j][r]);
            acc[i][j][r] = 0.0f;
          }
        }
    }
  }
  __syncthreads();

  // epilogue: Dir [64][144] u8 (direct tile), Tr [128][80] u8 (mirror) in sh;
  // S sums from dequantized values (rs = row/upper-inclusive, cs = col/strict-upper)
  u8* Dir = (u8*)sh;
  u8* Tr  = (u8*)sh + 64 * 144;
  float cs[4] = {0.f, 0.f, 0.f, 0.f};
#pragma unroll
  for (int i = 0; i < 2; ++i)
#pragma unroll
    for (int r = 0; r < 4; ++r) {
      int lrow = wr + i * 16 + lq * 4 + r;
      int grow = row0 + lrow;
      float rs = 0.0f;
#pragma unroll
      for (int j = 0; j < 4; ++j) {
        int lcol = wc + j * 16 + l15;
        int gcol = col0 + lcol;
        float val = __expf(emax[i][j][r] * 5.0f);
        if (grow == gcol) val = 0.0f;
        u8 q = f2fp8_hw(val);
        float dq = fp82f_hw(q);
        Dir[lrow * 144 + lcol] = q;
        bool strict = gcol > grow;
        Tr[lcol * 80 + lrow] = strict ? q : (u8)0;
        if (gcol >= grow) rs += dq;
        if (strict) cs[j] += dq;
      }
#pragma unroll
      for (int m = 1; m < 16; m <<= 1) rs += __shfl_xor(rs, m, 64);
      if (l15 == 0 && rs != 0.0f) atomicAdd(&S[grow], rs);
    }
#pragma unroll
  for (int j = 0; j < 4; ++j) {
    float c = cs[j];
    c += __shfl_xor(c, 16, 64);
    c += __shfl_xor(c, 32, 64);
    if (lq == 0 && c != 0.0f) atomicAdd(&S[col0 + wc + j * 16 + l15], c);
  }
  __syncthreads();
  if (col0 >= row0 + 64) {   // fully-upper tile: 16-B vector stores
    int c8 = threadIdx.x & 7, rr = threadIdx.x >> 3;
#pragma unroll
    for (int p = 0; p < 2; ++p) {
      int row = rr + p * 32;
      u32x4 ch = *(const u32x4*)(Dir + row * 144 + c8 * 16);
      *(u32x4*)(Abf + (size_t)(row0 + row) * NPAD + col0 + c8 * 16) = ch;
    }
    int c = threadIdx.x & 3; rr = threadIdx.x >> 2;
#pragma unroll
    for (int p = 0; p < 2; ++p) {
      int cc = rr + p * 64;
      u32x4 ch = *(const u32x4*)(Tr + cc * 80 + c * 16);
      *(u32x4*)(Abf + (size_t)(col0 + cc) * NPAD + row0 + c * 16) = ch;
    }
  } else {                    // straddle tile: predicated scalar
    for (int idx = threadIdx.x; idx < 64 * 128; idx += 256) {
      int row = idx >> 7, cc = idx & 127;
      int R = row0 + row, C = col0 + cc;
      u8 val = Dir[row * 144 + cc];
      if (C >= R) Abf[(size_t)R * NPAD + C] = val;
      if (C > R)  Abf[(size_t)C * NPAD + R] = val;
    }
  }
}

// partial[z] = Abf[:, zK:(z+1)K] @ hmT_all[:, zK:(z+1)K]^T  (fp8 operands, f32 acc,
// bf16 partials). XCD-swizzled flat grid. Ring-2 (32 KB -> 5 blocks/CU): stage
// issued AFTER the barrier (safe: all iter-(it-1) ds_reads consumed by MFMA
// before any wave reaches barrier(it)); loads fly under the MFMA cluster.
__global__ __launch_bounds__(256, 5) void k_pvsk(const u8* __restrict__ Abf, const u8* __restrict__ hmT,
                                                 u16* __restrict__ part) {
  __shared__ u8 sh8[2 * 2 * 128 * 64];   // [ring2][A/B][128][64] = 32 KB
  int lane = threadIdx.x & 63, wave = threadIdx.x >> 6;
  int bid = blockIdx.x;                  // 576 (12 dummy)
  int xcd = bid & 7, s = bid >> 3;
  int row = (s / 12) * 8 + xcd;
  if (row >= 47) return;
  int k = s % 12;
  int col0 = (k % 6) * 128, row0 = row * 128, kb = (k / 6) * (NPAD / 2);

  f32x4 acc[4][4];
  f32x4 z = {0.f, 0.f, 0.f, 0.f};
  for (int i = 0; i < 4; ++i) for (int j = 0; j < 4; ++j) acc[i][j] = z;

  const u8* Ap = Abf + (size_t)row0 * NPAD + kb;
  const u8* Bp = hmT + (size_t)col0 * NPAD + kb;
  auto pv_stage = [&](int it, u8* base) {
    stage8<128>(Ap + it * 64, NPAD, base, wave, lane);
    stage8<128>(Bp + it * 64, NPAD, base + 8192, wave, lane);
  };
  const int niter = (NPAD / 2) / 64;   // 47
  pv_stage(0, sh8);
  for (int it = 0; it < niter; ++it) {
    asm volatile("s_waitcnt vmcnt(0)" ::: "memory");
    __builtin_amdgcn_sched_barrier(0);
    __builtin_amdgcn_s_barrier();
    __builtin_amdgcn_sched_barrier(0);
    if (it + 1 < niter) pv_stage(it + 1, sh8 + ((it + 1) & 1) * 16384);
    u8* cur = sh8 + (it & 1) * 16384;
    __builtin_amdgcn_s_setprio(1);
    mfma_step8(cur, cur + 8192, acc, lane, wave);
    __builtin_amdgcn_s_setprio(0);
  }

  u16* pp = part + (size_t)(k / 6) * NPAD * (VV * HH);
  int wr = (wave >> 1) * 64, wc = (wave & 1) * 64, l15 = lane & 15, lq = lane >> 4;
#pragma unroll
  for (int i = 0; i < 4; ++i)
#pragma unroll
    for (int r = 0; r < 4; ++r) {
      int grow = row0 + wr + i * 16 + lq * 4 + r;
#pragma unroll
      for (int j = 0; j < 4; ++j) {
        int gcol = col0 + wc + j * 16 + l15;
        pp[(size_t)grow * (VV * HH) + gcol] = f2bf(acc[i][j][r]);
      }
    }
}

// newx = blend((p0+p1)/S, h); writes out_newx (f32) and nxb (bf16)
__global__ __launch_bounds__(256) void k_pvred(const u16* __restrict__ part, const float* __restrict__ S,
                                               const float* __restrict__ mT, const float* __restrict__ h,
                                               float* __restrict__ out_newx, u16* __restrict__ nxb) {
  int i = (blockIdx.x * 256 + threadIdx.x) * 4;
  int v = i / (NN * HH);
  int rem = i - v * (NN * HH);
  int n = rem / HH;
  int j = rem - n * HH;
  int col = v * HH + j;
  u16x4 p0 = *(const u16x4*)(part + (size_t)n * (VV * HH) + col);
  u16x4 p1 = *(const u16x4*)(part + (size_t)NPAD * (VV * HH) + (size_t)n * (VV * HH) + col);
  float sc = 1.0f / (S[n] + 1e-9f);
  float mrow = mT[v * NPAD + n];
  float4 o;
  o.x = (bf2f(p0[0]) + bf2f(p1[0])) * sc;
  o.y = (bf2f(p0[1]) + bf2f(p1[1])) * sc;
  o.z = (bf2f(p0[2]) + bf2f(p1[2])) * sc;
  o.w = (bf2f(p0[3]) + bf2f(p1[3])) * sc;
  if (mrow != 0.0f) o = *(const float4*)(h + (size_t)(v * NPAD + n) * HH + j);
  *(float4*)(out_newx + (size_t)(v * NN + n) * HH + j) = o;
  u16x4 ob = { f2bf(o.x), f2bf(o.y), f2bf(o.z), f2bf(o.w) };
  *(u16x4*)(nxb + (size_t)(v * NPAD + n) * HH + j) = ob;
}

// merged output GEMMs: bid<1128 -> x_new = leaky(new_x @ W_out^T + b_out), nan->0;
// bid>=1128 -> y_n = sigmoid(y @ Wy^T + by).
__global__ __launch_bounds__(256, 4) void k_out(const u16* __restrict__ nxb, const u16* __restrict__ woutb,
                                                const float* __restrict__ b_out,
                                                const u16* __restrict__ yb, const u16* __restrict__ wyb,
                                                const float* __restrict__ by,
                                                float* __restrict__ out_xnew, float* __restrict__ out_yn) {
  __shared__ u16 sh[3 * QK_BUF];
  int lane = threadIdx.x & 63, wave = threadIdx.x >> 6;
  int bid = blockIdx.x;
  f32x4 acc[2][4];
  f32x4 z = {0.f, 0.f, 0.f, 0.f};
  for (int i = 0; i < 2; ++i) for (int j = 0; j < 4; ++j) acc[i][j] = z;
  int wr = (wave >> 1) * 32, wc = (wave & 1) * 64, l15 = lane & 15, lq = lane >> 4;
  if (bid < 1128) {          // gemm3: grid (4 col, 94 row, 3 v) flattened
    int v = bid / 376, r2 = bid - v * 376;
    int col0 = (r2 & 3) * 128, row0 = (r2 >> 2) * 64;
    gemm_loop_r3(nxb + (size_t)(v * NPAD + row0) * HH, HH,
                 woutb + (size_t)(v * DD + col0) * HH, HH, HH, sh, acc, lane, wave);
#pragma unroll
    for (int i = 0; i < 2; ++i)
#pragma unroll
      for (int r = 0; r < 4; ++r) {
        int grow = row0 + wr + i * 16 + lq * 4 + r;
        if (grow < NN) {
#pragma unroll
          for (int j = 0; j < 4; ++j) {
            int gcol = col0 + wc + j * 16 + l15;
            float val = leaky(acc[i][j][r] + b_out[v * DD + gcol]);
            if (val != val) val = 0.0f;
            out_xnew[(size_t)(v * NN + grow) * DD + gcol] = val;
          }
        }
      }
  } else {                   // ygemm: grid (2 col, 94 row)
    int yid = bid - 1128;
    int col0 = (yid & 1) * 128, row0 = (yid >> 1) * 64;
    gemm_loop_r3(yb + (size_t)row0 * DYY, DYY,
                 wyb + (size_t)col0 * DYY, DYY, DYY, sh, acc, lane, wave);
#pragma unroll
    for (int i = 0; i < 2; ++i)
#pragma unroll
      for (int r = 0; r < 4; ++r) {
        int grow = row0 + wr + i * 16 + lq * 4 + r;
        if (grow < NN) {
#pragma unroll
          for (int j = 0; j < 4; ++j) {
            int gcol = col0 + wc + j * 16 + l15;
            float val = acc[i][j][r] + by[gcol];
            out_yn[(size_t)grow * HH + gcol] = 1.0f / (1.0f + __expf(-val));
          }
        }
      }
  }
}

// ---------------- launch ----------------

extern "C" void kernel_launch(void* const* d_in, const int* in_sizes, int n_in,
                              void* d_out, int out_size, void* d_ws, size_t ws_size,
                              hipStream_t stream) {
  const float* x    = (const float*)d_in[0];
  const float* y    = (const float*)d_in[1];
  const float* mask = (const float*)d_in[2];
  const float* W_in = (const float*)d_in[3];
  const float* b_in = (const float*)d_in[4];
  const float* W_out= (const float*)d_in[5];
  const float* b_out= (const float*)d_in[6];
  const float* Wy   = (const float*)d_in[7];
  const float* by   = (const float*)d_in[8];

  float* out_newx = (float*)d_out;
  float* out_xnew = out_newx + (size_t)VV * NN * HH;
  float* out_yn   = out_xnew + (size_t)VV * NN * DD;

  char* w = (char*)d_ws;
  size_t off = 0;
  auto alloc = [&](size_t bytes) -> void* {
    void* p = w + off;
    off += (bytes + 255) & ~(size_t)255;
    return p;
  };
  u16*   xb    = (u16*)alloc((size_t)VV * NPAD * DD * 2);
  u16*   yb    = (u16*)alloc((size_t)NPAD * DYY * 2);
  u16*   winb  = (u16*)alloc((size_t)VV * HH * DD * 2);
  u16*   woutb = (u16*)alloc((size_t)VV * DD * HH * 2);
  u16*   wyb   = (u16*)alloc((size_t)HH * DYY * 2);
  float* h     = (float*)alloc((size_t)VV * NPAD * HH * 4);
  u16*   qb    = (u16*)alloc((size_t)VV * NPAD * HH * 2);
  u8*    hmT   = (u8*)alloc((size_t)VV * HH * NPAD);
  u16*   nxb   = (u16*)alloc((size_t)VV * NPAD * HH * 2);
  float* mT    = (float*)alloc((size_t)VV * NPAD * 4);
  float* S     = (float*)alloc((size_t)NPAD * 4);
  u8*    Abf   = (u8*)alloc((size_t)NPAD * NPAD);
  // split-K partials (2 x NPAD x 768 bf16 = 18.48 MB) reuse xb, dead after k_gemm1
  u16*   pvp   = xb;
  (void)ws_size; (void)in_sizes; (void)n_in; (void)out_size;

  // merged conversions (4x conv + convx + mT)
  k_prep<<<(N_PREP + 255) / 256, 256, 0, stream>>>(x, y, mask, W_in, W_out, Wy,
                                                   xb, yb, winb, woutb, wyb, mT);
  hipMemsetAsync(S, 0, NPAD * sizeof(float), stream);

  // h, then fused q-norm + hmT
  k_gemm1<<<dim3(2, 94, 3), 256, 0, stream>>>(xb, winb, b_in, h);
  k_qh<<<dim3(94, 3), 256, 0, stream>>>(h, mT, qb, hmT);

  // attention (k_qk also accumulates S)
  k_qk<<<2256, 256, 0, stream>>>(qb, mT, Abf, S);
  k_pvsk<<<576, 256, 0, stream>>>(Abf, hmT, pvp);
  k_pvred<<<4500, 256, 0, stream>>>(pvp, S, mT, h, out_newx, nxb);

  // outputs: gemm3 (1128) + ygemm (188) in one dispatch
  k_out<<<1316, 256, 0, stream>>>(nxb, woutb, b_out, yb, wyb, by, out_xnew, out_yn);
}